// Round 8
// baseline (165.065 us; speedup 1.0000x reference)
//
#include <hip/hip_runtime.h>

typedef __bf16 bf16x8 __attribute__((ext_vector_type(8)));
typedef float  f32x4  __attribute__((ext_vector_type(4)));

#define MFMA(A, B, C) __builtin_amdgcn_mfma_f32_16x16x32_bf16((A), (B), (C), 0, 0, 0)

// Fused MLP: x=[h(64),b_in,b_out,J,-J] -> 64 relu -> 64 relu -> 5
// Out^T = W^T X^T per 16-row tile, rows at lane&15 (e), k-group q=lane>>4.
// R8 = R5 (best, 92.5us @ 16 waves/CU) with hybrid weight placement:
//  - layer1 weights (a1 8 frags + a1x 4 frags) in LDS, re-read per iter
//    (12 full ds_read_b128 vs R5's 22 -> ~45% less LDS-chain time)
//  - layer2/3 weights (a2 32 + a3 8 VGPRs) register-resident
//  - b2/b3 biases: LDS broadcast reads (4 addrs/wave, near-free)
//  - nontemporal loads for h/scalar streams + NT stores for out
//    (410MB stream >> L3, zero reuse)
// __launch_bounds__(256,4): 128-VGPR cap -> 16 waves/CU (proven optimum).
// LDS map: frag k (1KB each) 0..7=a1[mt][kk], 8..11=a1x[mt];
//          B2_OFF raw b2 (256B), B3_OFF padded b3 (64B).
#define B2_OFF 12288
#define B3_OFF 12544
__global__ __launch_bounds__(256, 4)
void msg_mlp(const float* __restrict__ hbuf, const float* __restrict__ Jbuf,
             const float* __restrict__ binb, const float* __restrict__ boutb,
             const float* __restrict__ W1, const float* __restrict__ b1,
             const float* __restrict__ W2, const float* __restrict__ b2,
             const float* __restrict__ W3, const float* __restrict__ b3,
             float* __restrict__ out, int n_rows, int n_tiles)
{
    __shared__ __align__(16) char wlds[12608];
    const int lane = threadIdx.x & 63;
    const int e = lane & 15;   // row-within-tile (B n-index and D col)
    const int q = lane >> 4;   // k-group
    const int wv = (int)(threadIdx.x >> 6);
    const int wid = blockIdx.x * 4 + wv;
    const int nw  = gridDim.x * 4;
    char* slot = wlds + lane * 16;           // + frag*1024

    // ---------------- LDS init (layer1 weights + biases), split by wave ----------------
    if (wv == 0) {               // a1 (8 frags), f = 16q + 8kk + i
#pragma unroll
      for (int mt = 0; mt < 4; ++mt)
#pragma unroll
        for (int kk = 0; kk < 2; ++kk) {
          bf16x8 v;
#pragma unroll
          for (int i = 0; i < 8; ++i)
            v[i] = (__bf16)W1[(16*q + 8*kk + i)*64 + 16*mt + e];
          *(bf16x8*)(slot + (mt*2 + kk) * 1024) = v;
        }
    } else if (wv == 1) {        // a1x (4 frags): scalar-feature col + bias col
#pragma unroll
      for (int mt = 0; mt < 4; ++mt) {
        const int o = 16*mt + e;
        float w0;
        if      (q == 0) w0 =  W1[64*64 + o];   // b_in
        else if (q == 1) w0 =  W1[65*64 + o];   // b_out
        else if (q == 2) w0 =  W1[66*64 + o];   // J
        else             w0 = -W1[67*64 + o];   // -J: sign folded into weight
        bf16x8 v;
        v[0] = (__bf16)w0;
        v[1] = (q == 0) ? (__bf16)b1[o] : (__bf16)0.0f;
#pragma unroll
        for (int i = 2; i < 8; ++i) v[i] = (__bf16)0.0f;
        *(bf16x8*)(slot + (8 + mt) * 1024) = v;
      }
    } else if (wv == 2) {        // b2 raw copy (64 floats)
      ((float*)(wlds + B2_OFF))[lane] = b2[lane];
    } else {                     // b3 padded copy (16 floats)
      if (lane < 16)
        ((float*)(wlds + B3_OFF))[lane] = (lane < 5) ? b3[lane] : 0.0f;
    }

    // ---------------- register-resident layer2/3 weights (40 VGPRs) ----------------
    bf16x8 a2[4][2];   // layer2: f = 16*(2kk+(i>>2)) + 4q + (i&3)
#pragma unroll
    for (int mt = 0; mt < 4; ++mt)
#pragma unroll
      for (int kk = 0; kk < 2; ++kk)
#pragma unroll
        for (int i = 0; i < 8; ++i) {
          const int f = 16*(2*kk + (i>>2)) + 4*q + (i&3);
          a2[mt][kk][i] = (__bf16)W2[f*64 + 16*mt + e];
        }
    bf16x8 a3[2];      // layer3: 5 outs (rest zero)
#pragma unroll
    for (int kk = 0; kk < 2; ++kk)
#pragma unroll
      for (int i = 0; i < 8; ++i) {
        const int f = 16*(2*kk + (i>>2)) + 4*q + (i&3);
        a3[kk][i] = (e < 5) ? (__bf16)W3[f*5 + e] : (__bf16)0.0f;
      }

    // per-lane uniform scalar stream (no divergence; q>=2 reads +J, sign in weight)
    const float* sptr = (q == 0) ? binb : (q == 1) ? boutb : Jbuf;
    const __bf16 biasf = (q == 0) ? (__bf16)1.0f : (__bf16)0.0f;

    __syncthreads();

    // ---------------- main loop: grid-stride, pure TLP ----------------
#pragma unroll 1
    for (int t = wid; t < n_tiles; t += nw) {
      int z0 = 0;
      asm volatile("" : "+s"(z0));           // opaque 0: defeat LICM on LDS reads
      const char* Wf = slot + z0;                       // frag base (+imm offsets)
      const char* Wb = wlds + 16*q + z0;                // bias base  (+imm offsets)

      int re = t * 16 + e;
      if (re >= n_rows) re = n_rows - 1;     // clamp (garbage compute, store guarded)
      const float* hr = hbuf + (size_t)re * 64 + q * 16;
      const f32x4 v0 = __builtin_nontemporal_load((const f32x4*)(hr));
      const f32x4 v1 = __builtin_nontemporal_load((const f32x4*)(hr + 4));
      const f32x4 v2 = __builtin_nontemporal_load((const f32x4*)(hr + 8));
      const f32x4 v3 = __builtin_nontemporal_load((const f32x4*)(hr + 12));
      const float s  = __builtin_nontemporal_load(sptr + re);

      // pack x -> bf16 B-fragments
      bf16x8 xb0, xb1, xb2;
#pragma unroll
      for (int i = 0; i < 4; ++i) {
        xb0[i]     = (__bf16)v0[i];
        xb0[i + 4] = (__bf16)v1[i];
        xb1[i]     = (__bf16)v2[i];
        xb1[i + 4] = (__bf16)v3[i];
      }
      xb2[0] = (__bf16)s; xb2[1] = biasf;
#pragma unroll
      for (int i = 2; i < 8; ++i) xb2[i] = (__bf16)0.0f;

      // ---- layer 1: [68->64] + relu (weights from LDS) ----
      f32x4 acc1[4];
#pragma unroll
      for (int mt = 0; mt < 4; ++mt) {
        const bf16x8 wa = *(const bf16x8*)(Wf + (mt*2 + 0) * 1024);
        const bf16x8 wb = *(const bf16x8*)(Wf + (mt*2 + 1) * 1024);
        const bf16x8 wx = *(const bf16x8*)(Wf + (8 + mt)  * 1024);
        acc1[mt] = (f32x4){0.f, 0.f, 0.f, 0.f};
        acc1[mt] = MFMA(wa, xb0, acc1[mt]);
        acc1[mt] = MFMA(wb, xb1, acc1[mt]);
        acc1[mt] = MFMA(wx, xb2, acc1[mt]);
      }
      bf16x8 y[2];   // lane-local repack: y[kk][i] = relu(acc1[2kk+(i>>2)][i&3])
#pragma unroll
      for (int kk = 0; kk < 2; ++kk)
#pragma unroll
        for (int i = 0; i < 8; ++i)
          y[kk][i] = (__bf16)fmaxf(acc1[2*kk + (i>>2)][i & 3], 0.0f);

      // ---- layer 2: [64->64] + relu (register weights, LDS broadcast bias) ----
      f32x4 acc2[4];
#pragma unroll
      for (int mt = 0; mt < 4; ++mt) {
        acc2[mt] = *(const f32x4*)(Wb + B2_OFF + 64*mt);
        acc2[mt] = MFMA(a2[mt][0], y[0], acc2[mt]);
        acc2[mt] = MFMA(a2[mt][1], y[1], acc2[mt]);
      }
      bf16x8 z[2];
#pragma unroll
      for (int kk = 0; kk < 2; ++kk)
#pragma unroll
        for (int i = 0; i < 8; ++i)
          z[kk][i] = (__bf16)fmaxf(acc2[2*kk + (i>>2)][i & 3], 0.0f);

      // ---- layer 3: [64->5] ----
      f32x4 acc3 = *(const f32x4*)(Wb + B3_OFF);
      acc3 = MFMA(a3[0], z[0], acc3);
      acc3 = MFMA(a3[1], z[1], acc3);

      // ---- store: out feature m = 4q+r, row = 16t+e (NT, write-once) ----
      const int rowi = t * 16 + e;
      if (rowi < n_rows) {
        float* orow = out + (size_t)rowi * 5;
        if (q == 0) {
          __builtin_nontemporal_store(acc3[0], orow + 0);
          __builtin_nontemporal_store(acc3[1], orow + 1);
          __builtin_nontemporal_store(acc3[2], orow + 2);
          __builtin_nontemporal_store(acc3[3], orow + 3);
        } else if (q == 1) {
          __builtin_nontemporal_store(acc3[0], orow + 4);
        }
      }
    }
}

extern "C" void kernel_launch(void* const* d_in, const int* in_sizes, int n_in,
                              void* d_out, int out_size, void* d_ws, size_t ws_size,
                              hipStream_t stream) {
    const float* h     = (const float*)d_in[0];
    const float* J     = (const float*)d_in[1];
    const float* b_in  = (const float*)d_in[2];
    const float* b_out = (const float*)d_in[3];
    const float* W1    = (const float*)d_in[4];
    const float* b1    = (const float*)d_in[5];
    const float* W2    = (const float*)d_in[6];
    const float* b2    = (const float*)d_in[7];
    const float* W3    = (const float*)d_in[8];
    const float* b3    = (const float*)d_in[9];
    float* out = (float*)d_out;

    const int n_rows  = in_sizes[1];            // J has B*E elements
    const int n_tiles = (n_rows + 15) / 16;

    // R5's proven config: 1024 blocks x 4 waves = 4096 waves = 16 waves/CU.
    dim3 grid(1024), block(256);
    hipLaunchKernelGGL(msg_mlp, grid, block, 0, stream,
                       h, J, b_in, b_out, W1, b1, W2, b2, W3, b3,
                       out, n_rows, n_tiles);
}

// Round 9
// 107.648 us; speedup vs baseline: 1.5334x; 1.5334x over previous
//
#include <hip/hip_runtime.h>

typedef __bf16 bf16x8 __attribute__((ext_vector_type(8)));
typedef float  f32x4  __attribute__((ext_vector_type(4)));

#define MFMA(A, B, C) __builtin_amdgcn_mfma_f32_16x16x32_bf16((A), (B), (C), 0, 0, 0)

// Fused MLP: x=[h(64),b_in,b_out,J,-J] -> 64 relu -> 64 relu -> 5
// Out^T = W^T X^T per 16-row tile, rows at lane&15 (e), k-group q=lane>>4.
// R9 = R8 minus ALL nontemporal hints (single-variable test of the hybrid
// weight placement; R8's 165us regression attributed to NT stores defeating
// L2 write-combining on the 20B/row scattered output).
//  - layer1 weights (a1 8 frags + a1x 4 frags) in LDS, re-read per iter
//    (12 full ds_read_b128 vs R5's 22)
//  - layer2/3 weights (a2 32 + a3 8 VGPRs) register-resident
//  - b2/b3 biases: LDS broadcast reads
// __launch_bounds__(256,4): 128-VGPR cap -> 16 waves/CU (proven optimum).
// LDS map: frag k (1KB each) 0..7=a1[mt][kk], 8..11=a1x[mt];
//          B2_OFF raw b2 (256B), B3_OFF padded b3 (64B).
#define B2_OFF 12288
#define B3_OFF 12544
__global__ __launch_bounds__(256, 4)
void msg_mlp(const float* __restrict__ hbuf, const float* __restrict__ Jbuf,
             const float* __restrict__ binb, const float* __restrict__ boutb,
             const float* __restrict__ W1, const float* __restrict__ b1,
             const float* __restrict__ W2, const float* __restrict__ b2,
             const float* __restrict__ W3, const float* __restrict__ b3,
             float* __restrict__ out, int n_rows, int n_tiles)
{
    __shared__ __align__(16) char wlds[12608];
    const int lane = threadIdx.x & 63;
    const int e = lane & 15;   // row-within-tile (B n-index and D col)
    const int q = lane >> 4;   // k-group
    const int wv = (int)(threadIdx.x >> 6);
    const int wid = blockIdx.x * 4 + wv;
    const int nw  = gridDim.x * 4;
    char* slot = wlds + lane * 16;           // + frag*1024

    // ---------------- LDS init (layer1 weights + biases), split by wave ----------------
    if (wv == 0) {               // a1 (8 frags), f = 16q + 8kk + i
#pragma unroll
      for (int mt = 0; mt < 4; ++mt)
#pragma unroll
        for (int kk = 0; kk < 2; ++kk) {
          bf16x8 v;
#pragma unroll
          for (int i = 0; i < 8; ++i)
            v[i] = (__bf16)W1[(16*q + 8*kk + i)*64 + 16*mt + e];
          *(bf16x8*)(slot + (mt*2 + kk) * 1024) = v;
        }
    } else if (wv == 1) {        // a1x (4 frags): scalar-feature col + bias col
#pragma unroll
      for (int mt = 0; mt < 4; ++mt) {
        const int o = 16*mt + e;
        float w0;
        if      (q == 0) w0 =  W1[64*64 + o];   // b_in
        else if (q == 1) w0 =  W1[65*64 + o];   // b_out
        else if (q == 2) w0 =  W1[66*64 + o];   // J
        else             w0 = -W1[67*64 + o];   // -J: sign folded into weight
        bf16x8 v;
        v[0] = (__bf16)w0;
        v[1] = (q == 0) ? (__bf16)b1[o] : (__bf16)0.0f;
#pragma unroll
        for (int i = 2; i < 8; ++i) v[i] = (__bf16)0.0f;
        *(bf16x8*)(slot + (8 + mt) * 1024) = v;
      }
    } else if (wv == 2) {        // b2 raw copy (64 floats)
      ((float*)(wlds + B2_OFF))[lane] = b2[lane];
    } else {                     // b3 padded copy (16 floats)
      if (lane < 16)
        ((float*)(wlds + B3_OFF))[lane] = (lane < 5) ? b3[lane] : 0.0f;
    }

    // ---------------- register-resident layer2/3 weights (40 VGPRs) ----------------
    bf16x8 a2[4][2];   // layer2: f = 16*(2kk+(i>>2)) + 4q + (i&3)
#pragma unroll
    for (int mt = 0; mt < 4; ++mt)
#pragma unroll
      for (int kk = 0; kk < 2; ++kk)
#pragma unroll
        for (int i = 0; i < 8; ++i) {
          const int f = 16*(2*kk + (i>>2)) + 4*q + (i&3);
          a2[mt][kk][i] = (__bf16)W2[f*64 + 16*mt + e];
        }
    bf16x8 a3[2];      // layer3: 5 outs (rest zero)
#pragma unroll
    for (int kk = 0; kk < 2; ++kk)
#pragma unroll
      for (int i = 0; i < 8; ++i) {
        const int f = 16*(2*kk + (i>>2)) + 4*q + (i&3);
        a3[kk][i] = (e < 5) ? (__bf16)W3[f*5 + e] : (__bf16)0.0f;
      }

    // per-lane uniform scalar stream (no divergence; q>=2 reads +J, sign in weight)
    const float* sptr = (q == 0) ? binb : (q == 1) ? boutb : Jbuf;
    const __bf16 biasf = (q == 0) ? (__bf16)1.0f : (__bf16)0.0f;

    __syncthreads();

    // ---------------- main loop: grid-stride, pure TLP ----------------
#pragma unroll 1
    for (int t = wid; t < n_tiles; t += nw) {
      int z0 = 0;
      asm volatile("" : "+s"(z0));           // opaque 0: defeat LICM on LDS reads
      const char* Wf = slot + z0;                       // frag base (+imm offsets)
      const char* Wb = wlds + 16*q + z0;                // bias base  (+imm offsets)

      int re = t * 16 + e;
      if (re >= n_rows) re = n_rows - 1;     // clamp (garbage compute, store guarded)
      const float* hr = hbuf + (size_t)re * 64 + q * 16;
      const f32x4 v0 = *(const f32x4*)(hr);
      const f32x4 v1 = *(const f32x4*)(hr + 4);
      const f32x4 v2 = *(const f32x4*)(hr + 8);
      const f32x4 v3 = *(const f32x4*)(hr + 12);
      const float s  = sptr[re];

      // pack x -> bf16 B-fragments
      bf16x8 xb0, xb1, xb2;
#pragma unroll
      for (int i = 0; i < 4; ++i) {
        xb0[i]     = (__bf16)v0[i];
        xb0[i + 4] = (__bf16)v1[i];
        xb1[i]     = (__bf16)v2[i];
        xb1[i + 4] = (__bf16)v3[i];
      }
      xb2[0] = (__bf16)s; xb2[1] = biasf;
#pragma unroll
      for (int i = 2; i < 8; ++i) xb2[i] = (__bf16)0.0f;

      // ---- layer 1: [68->64] + relu (weights from LDS) ----
      f32x4 acc1[4];
#pragma unroll
      for (int mt = 0; mt < 4; ++mt) {
        const bf16x8 wa = *(const bf16x8*)(Wf + (mt*2 + 0) * 1024);
        const bf16x8 wb = *(const bf16x8*)(Wf + (mt*2 + 1) * 1024);
        const bf16x8 wx = *(const bf16x8*)(Wf + (8 + mt)  * 1024);
        acc1[mt] = (f32x4){0.f, 0.f, 0.f, 0.f};
        acc1[mt] = MFMA(wa, xb0, acc1[mt]);
        acc1[mt] = MFMA(wb, xb1, acc1[mt]);
        acc1[mt] = MFMA(wx, xb2, acc1[mt]);
      }
      bf16x8 y[2];   // lane-local repack: y[kk][i] = relu(acc1[2kk+(i>>2)][i&3])
#pragma unroll
      for (int kk = 0; kk < 2; ++kk)
#pragma unroll
        for (int i = 0; i < 8; ++i)
          y[kk][i] = (__bf16)fmaxf(acc1[2*kk + (i>>2)][i & 3], 0.0f);

      // ---- layer 2: [64->64] + relu (register weights, LDS broadcast bias) ----
      f32x4 acc2[4];
#pragma unroll
      for (int mt = 0; mt < 4; ++mt) {
        acc2[mt] = *(const f32x4*)(Wb + B2_OFF + 64*mt);
        acc2[mt] = MFMA(a2[mt][0], y[0], acc2[mt]);
        acc2[mt] = MFMA(a2[mt][1], y[1], acc2[mt]);
      }
      bf16x8 z[2];
#pragma unroll
      for (int kk = 0; kk < 2; ++kk)
#pragma unroll
        for (int i = 0; i < 8; ++i)
          z[kk][i] = (__bf16)fmaxf(acc2[2*kk + (i>>2)][i & 3], 0.0f);

      // ---- layer 3: [64->5] ----
      f32x4 acc3 = *(const f32x4*)(Wb + B3_OFF);
      acc3 = MFMA(a3[0], z[0], acc3);
      acc3 = MFMA(a3[1], z[1], acc3);

      // ---- store: out feature m = 4q+r, row = 16t+e (plain stores!) ----
      const int rowi = t * 16 + e;
      if (rowi < n_rows) {
        float* orow = out + (size_t)rowi * 5;
        if (q == 0) {
          orow[0] = acc3[0]; orow[1] = acc3[1];
          orow[2] = acc3[2]; orow[3] = acc3[3];
        } else if (q == 1) {
          orow[4] = acc3[0];
        }
      }
    }
}

extern "C" void kernel_launch(void* const* d_in, const int* in_sizes, int n_in,
                              void* d_out, int out_size, void* d_ws, size_t ws_size,
                              hipStream_t stream) {
    const float* h     = (const float*)d_in[0];
    const float* J     = (const float*)d_in[1];
    const float* b_in  = (const float*)d_in[2];
    const float* b_out = (const float*)d_in[3];
    const float* W1    = (const float*)d_in[4];
    const float* b1    = (const float*)d_in[5];
    const float* W2    = (const float*)d_in[6];
    const float* b2    = (const float*)d_in[7];
    const float* W3    = (const float*)d_in[8];
    const float* b3    = (const float*)d_in[9];
    float* out = (float*)d_out;

    const int n_rows  = in_sizes[1];            // J has B*E elements
    const int n_tiles = (n_rows + 15) / 16;

    // R5's proven config: 1024 blocks x 4 waves = 4096 waves = 16 waves/CU.
    dim3 grid(1024), block(256);
    hipLaunchKernelGGL(msg_mlp, grid, block, 0, stream,
                       h, J, b_in, b_out, W1, b1, W2, b2, W3, b3,
                       out, n_rows, n_tiles);
}

// Round 10
// 92.585 us; speedup vs baseline: 1.7828x; 1.1627x over previous
//
#include <hip/hip_runtime.h>

typedef __bf16 bf16x8 __attribute__((ext_vector_type(8)));
typedef float  f32x4  __attribute__((ext_vector_type(4)));

#define MFMA(A, B, C) __builtin_amdgcn_mfma_f32_16x16x32_bf16((A), (B), (C), 0, 0, 0)

// Fused MLP: x=[h(64),b_in,b_out,J,-J] -> 64 relu -> 64 relu -> 5
// Out^T = W^T X^T per 16-row tile, rows at lane&15 (e), k-group q=lane>>4.
// R10 = exact revert to R5 (best measured: 92.5us, 4.99 TB/s).
// Weights live in LDS (27 frag-slots x 1KB, fragment layout, re-read per
// tile via conflict-free lane*16 ds_read_b128): VGPR <= 128 -> 16 waves/CU.
// Axis results (R1-R9): occupancy 8->97us 16->92.5 20->95.3 32->102(spill);
// addr pattern / pipeline depth: no effect; hybrid reg weights: -15us worse;
// NT stores: -57us worse (defeat L2 write-combining on 20B/row output).
// Frag slot map (1KB each):
//   a1[mt][kk] -> mt*2+kk   (0..7)    layer1 h-weights, f = 16q+8kk+i
//   a1x[mt]    -> 8+mt      (8..11)   layer1 scalar-feat + bias column
//   a2[mt][kk] -> 12+mt*2+kk(12..19)  layer2, f = 16*(2kk+(i>>2))+4q+(i&3)
//   a3[kk]     -> 20+kk     (20..21)  layer3
//   b2r[mt]    -> 22+mt     (22..25)  f32x4 bias, out = 16mt+4q+r
//   b3r        -> 26                  f32x4 bias
__global__ __launch_bounds__(256, 4)
void msg_mlp(const float* __restrict__ hbuf, const float* __restrict__ Jbuf,
             const float* __restrict__ binb, const float* __restrict__ boutb,
             const float* __restrict__ W1, const float* __restrict__ b1,
             const float* __restrict__ W2, const float* __restrict__ b2,
             const float* __restrict__ W3, const float* __restrict__ b3,
             float* __restrict__ out, int n_rows, int n_tiles)
{
    __shared__ __align__(16) char wlds[27 * 1024];
    const int lane = threadIdx.x & 63;
    const int e = lane & 15;   // row-within-tile (B n-index and D col)
    const int q = lane >> 4;   // k-group
    const int wv = (int)(threadIdx.x >> 6);
    const int wid = blockIdx.x * 4 + wv;
    const int nw  = gridDim.x * 4;
    char* slot = wlds + lane * 16;           // + frag*1024

    // ---------------- weight-fragment init (split across the 4 waves) ----------------
    if (wv == 0) {               // a1 (8 frags) + a1x (4 frags)
#pragma unroll
      for (int mt = 0; mt < 4; ++mt)
#pragma unroll
        for (int kk = 0; kk < 2; ++kk) {
          bf16x8 v;
#pragma unroll
          for (int i = 0; i < 8; ++i)
            v[i] = (__bf16)W1[(16*q + 8*kk + i)*64 + 16*mt + e];
          *(bf16x8*)(slot + (mt*2 + kk) * 1024) = v;
        }
#pragma unroll
      for (int mt = 0; mt < 4; ++mt) {
        const int o = 16*mt + e;
        float w0;
        if      (q == 0) w0 =  W1[64*64 + o];   // b_in
        else if (q == 1) w0 =  W1[65*64 + o];   // b_out
        else if (q == 2) w0 =  W1[66*64 + o];   // J
        else             w0 = -W1[67*64 + o];   // -J: sign folded into weight
        bf16x8 v;
        v[0] = (__bf16)w0;
        v[1] = (q == 0) ? (__bf16)b1[o] : (__bf16)0.0f;
#pragma unroll
        for (int i = 2; i < 8; ++i) v[i] = (__bf16)0.0f;
        *(bf16x8*)(slot + (8 + mt) * 1024) = v;
      }
    } else if (wv == 1) {        // a2 (8 frags)
#pragma unroll
      for (int mt = 0; mt < 4; ++mt)
#pragma unroll
        for (int kk = 0; kk < 2; ++kk) {
          bf16x8 v;
#pragma unroll
          for (int i = 0; i < 8; ++i) {
            const int f = 16*(2*kk + (i>>2)) + 4*q + (i&3);
            v[i] = (__bf16)W2[f*64 + 16*mt + e];
          }
          *(bf16x8*)(slot + (12 + mt*2 + kk) * 1024) = v;
        }
    } else if (wv == 2) {        // a3 (2 frags) + b3r
#pragma unroll
      for (int kk = 0; kk < 2; ++kk) {
        bf16x8 v;
#pragma unroll
        for (int i = 0; i < 8; ++i) {
          const int f = 16*(2*kk + (i>>2)) + 4*q + (i&3);
          v[i] = (e < 5) ? (__bf16)W3[f*5 + e] : (__bf16)0.0f;
        }
        *(bf16x8*)(slot + (20 + kk) * 1024) = v;
      }
      f32x4 v3;
#pragma unroll
      for (int r = 0; r < 4; ++r) v3[r] = (4*q + r < 5) ? b3[4*q + r] : 0.0f;
      *(f32x4*)(slot + 26 * 1024) = v3;
    } else {                     // b2r (4 frags)
#pragma unroll
      for (int mt = 0; mt < 4; ++mt) {
        f32x4 v;
#pragma unroll
        for (int r = 0; r < 4; ++r) v[r] = b2[16*mt + 4*q + r];
        *(f32x4*)(slot + (22 + mt) * 1024) = v;
      }
    }

    // per-lane uniform scalar stream (no divergence; q>=2 reads +J, sign in weight)
    const float* sptr = (q == 0) ? binb : (q == 1) ? boutb : Jbuf;
    const __bf16 biasf = (q == 0) ? (__bf16)1.0f : (__bf16)0.0f;

    __syncthreads();

    // ---------------- main loop: grid-stride, no SW pipeline (TLP covers latency) ----------------
#pragma unroll 1
    for (int t = wid; t < n_tiles; t += nw) {
      int z0 = 0;
      asm volatile("" : "+s"(z0));           // opaque 0: defeat LICM on weight reads
      const char* Wf = slot + z0;

      int re = t * 16 + e;
      if (re >= n_rows) re = n_rows - 1;     // clamp (garbage compute, store guarded)
      const float* hr = hbuf + (size_t)re * 64 + q * 16;
      const f32x4 v0 = *(const f32x4*)(hr);
      const f32x4 v1 = *(const f32x4*)(hr + 4);
      const f32x4 v2 = *(const f32x4*)(hr + 8);
      const f32x4 v3 = *(const f32x4*)(hr + 12);
      const float s  = sptr[re];

      // pack x -> bf16 B-fragments
      bf16x8 xb0, xb1, xb2;
#pragma unroll
      for (int i = 0; i < 4; ++i) {
        xb0[i]     = (__bf16)v0[i];
        xb0[i + 4] = (__bf16)v1[i];
        xb1[i]     = (__bf16)v2[i];
        xb1[i + 4] = (__bf16)v3[i];
      }
      xb2[0] = (__bf16)s; xb2[1] = biasf;
#pragma unroll
      for (int i = 2; i < 8; ++i) xb2[i] = (__bf16)0.0f;

      // ---- layer 1: [68->64] + relu ----
      f32x4 acc1[4];
#pragma unroll
      for (int mt = 0; mt < 4; ++mt) {
        const bf16x8 wa = *(const bf16x8*)(Wf + (mt*2 + 0) * 1024);
        const bf16x8 wb = *(const bf16x8*)(Wf + (mt*2 + 1) * 1024);
        const bf16x8 wx = *(const bf16x8*)(Wf + (8 + mt)  * 1024);
        acc1[mt] = (f32x4){0.f, 0.f, 0.f, 0.f};
        acc1[mt] = MFMA(wa, xb0, acc1[mt]);
        acc1[mt] = MFMA(wb, xb1, acc1[mt]);
        acc1[mt] = MFMA(wx, xb2, acc1[mt]);
      }
      bf16x8 y[2];   // lane-local repack: y[kk][i] = relu(acc1[2kk+(i>>2)][i&3])
#pragma unroll
      for (int kk = 0; kk < 2; ++kk)
#pragma unroll
        for (int i = 0; i < 8; ++i)
          y[kk][i] = (__bf16)fmaxf(acc1[2*kk + (i>>2)][i & 3], 0.0f);

      // ---- layer 2: [64->64] + relu ----
      f32x4 acc2[4];
#pragma unroll
      for (int mt = 0; mt < 4; ++mt) {
        const bf16x8 wa = *(const bf16x8*)(Wf + (12 + mt*2 + 0) * 1024);
        const bf16x8 wb = *(const bf16x8*)(Wf + (12 + mt*2 + 1) * 1024);
        acc2[mt] = *(const f32x4*)(Wf + (22 + mt) * 1024);
        acc2[mt] = MFMA(wa, y[0], acc2[mt]);
        acc2[mt] = MFMA(wb, y[1], acc2[mt]);
      }
      bf16x8 z[2];
#pragma unroll
      for (int kk = 0; kk < 2; ++kk)
#pragma unroll
        for (int i = 0; i < 8; ++i)
          z[kk][i] = (__bf16)fmaxf(acc2[2*kk + (i>>2)][i & 3], 0.0f);

      // ---- layer 3: [64->5] ----
      f32x4 acc3 = *(const f32x4*)(Wf + 26 * 1024);
      acc3 = MFMA(*(const bf16x8*)(Wf + 20 * 1024), z[0], acc3);
      acc3 = MFMA(*(const bf16x8*)(Wf + 21 * 1024), z[1], acc3);

      // ---- store: out feature m = 4q+r, row = 16t+e ----
      const int rowi = t * 16 + e;
      if (rowi < n_rows) {
        float* orow = out + (size_t)rowi * 5;
        if (q == 0) {
          orow[0] = acc3[0]; orow[1] = acc3[1];
          orow[2] = acc3[2]; orow[3] = acc3[3];
        } else if (q == 1) {
          orow[4] = acc3[0];
        }
      }
    }
}

extern "C" void kernel_launch(void* const* d_in, const int* in_sizes, int n_in,
                              void* d_out, int out_size, void* d_ws, size_t ws_size,
                              hipStream_t stream) {
    const float* h     = (const float*)d_in[0];
    const float* J     = (const float*)d_in[1];
    const float* b_in  = (const float*)d_in[2];
    const float* b_out = (const float*)d_in[3];
    const float* W1    = (const float*)d_in[4];
    const float* b1    = (const float*)d_in[5];
    const float* W2    = (const float*)d_in[6];
    const float* b2    = (const float*)d_in[7];
    const float* W3    = (const float*)d_in[8];
    const float* b3    = (const float*)d_in[9];
    float* out = (float*)d_out;

    const int n_rows  = in_sizes[1];            // J has B*E elements
    const int n_tiles = (n_rows + 15) / 16;

    // 1024 blocks x 4 waves = 4096 waves = 16 waves/CU x 256 CUs exactly
    dim3 grid(1024), block(256);
    hipLaunchKernelGGL(msg_mlp, grid, block, 0, stream,
                       h, J, b_in, b_out, W1, b1, W2, b2, W3, b3,
                       out, n_rows, n_tiles);
}